// Round 4
// baseline (461.093 us; speedup 1.0000x reference)
//
#include <hip/hip_runtime.h>

// Shape: l=8, p=1, m=4096, n=1024. One thread per row (32768 rows = 512 waves,
// 2 waves/CU — structural). Recurrence w[k] = w[k-1] + a/w[k-1] - b*x[k-1].
//
// NUMERICS ARE LOAD-BEARING: the map is chaotic (dw'/dw = 1 - a/w^2 explodes
// near w ~ sqrt(a)); rcp+NR (~1ulp/step) amplified to absmax 164k (R2) vs
// threshold 1597. Bitwise-IEEE __fdiv_rn/__fadd_rn/__fsub_rn/__fmul_rn in the
// exact numpy association gave absmax 0.0 (R0). Do not relax these.
//
// R3: R0 spilled its 3x16-float local arrays to scratch (VGPR_Count=28 —
// impossible for 48 live floats) -> ~290 cyc/step wall vs 27 cyc/step VALU
// issue. This version uses ONLY explicit ext_vector register variables:
// 4x float4 current chunk, 4x float4 prefetch, 1x float4 output staging.

#define N_COLS 1024

typedef float vf4 __attribute__((ext_vector_type(4)));  // native vec: regs + NT store ok

__device__ __forceinline__ float stepf(float w, float bx, float a) {
    // ((w + (a/w)) - (b*x)) with b*x precomputed via __fmul_rn off-chain.
    return __fsub_rn(__fadd_rn(w, __fdiv_rn(a, w)), bx);
}

__global__ __launch_bounds__(64) void DDK_77644418777662_kernel(
    const float* __restrict__ in, float* __restrict__ out,
    const float* __restrict__ alpha, const float* __restrict__ beta,
    int n_rows) {
    int row = blockIdx.x * 64 + threadIdx.x;
    if (row >= n_rows) return;

    const float a = alpha[0];
    const float b = beta[0];

    const vf4* __restrict__ inr =
        reinterpret_cast<const vf4*>(in + (size_t)row * N_COLS);
    vf4* __restrict__ outr = reinterpret_cast<vf4*>(out + (size_t)row * N_COLS);

    // 64 chunks of 16 floats (4 x float4) per row.
    vf4 c0 = inr[0], c1 = inr[1], c2 = inr[2], c3 = inr[3];
    float w = 1.0f;

    for (int j = 0; j < 64; ++j) {
        // Branchless prefetch of next chunk (clamped on last iter; loads are
        // independent of the recurrence chain and stay in flight under it).
        int jn = (j < 63) ? (j + 1) : 63;
        const vf4* __restrict__ pn = inr + (size_t)jn * 4;
        vf4 n0 = pn[0], n1 = pn[1], n2 = pn[2], n3 = pn[3];

        // Off-chain b*x products (exact __fmul_rn, kept un-fused).
        vf4 bx0, bx1, bx2, bx3;
        bx0.x = __fmul_rn(b, c0.x); bx0.y = __fmul_rn(b, c0.y);
        bx0.z = __fmul_rn(b, c0.z); bx0.w = __fmul_rn(b, c0.w);
        bx1.x = __fmul_rn(b, c1.x); bx1.y = __fmul_rn(b, c1.y);
        bx1.z = __fmul_rn(b, c1.z); bx1.w = __fmul_rn(b, c1.w);
        bx2.x = __fmul_rn(b, c2.x); bx2.y = __fmul_rn(b, c2.y);
        bx2.z = __fmul_rn(b, c2.z); bx2.w = __fmul_rn(b, c2.w);
        bx3.x = __fmul_rn(b, c3.x); bx3.y = __fmul_rn(b, c3.y);
        bx3.z = __fmul_rn(b, c3.z); bx3.w = __fmul_rn(b, c3.w);

        vf4 o;
        // outputs 16j .. 16j+15; o holds 4 at a time, stored when full.
        o.x = w;
        w = stepf(w, bx0.x, a); o.y = w;
        w = stepf(w, bx0.y, a); o.z = w;
        w = stepf(w, bx0.z, a); o.w = w;
        __builtin_nontemporal_store(o, &outr[(size_t)j * 4 + 0]);

        w = stepf(w, bx0.w, a); o.x = w;
        w = stepf(w, bx1.x, a); o.y = w;
        w = stepf(w, bx1.y, a); o.z = w;
        w = stepf(w, bx1.z, a); o.w = w;
        __builtin_nontemporal_store(o, &outr[(size_t)j * 4 + 1]);

        w = stepf(w, bx1.w, a); o.x = w;
        w = stepf(w, bx2.x, a); o.y = w;
        w = stepf(w, bx2.y, a); o.z = w;
        w = stepf(w, bx2.z, a); o.w = w;
        __builtin_nontemporal_store(o, &outr[(size_t)j * 4 + 2]);

        w = stepf(w, bx2.w, a); o.x = w;
        w = stepf(w, bx3.x, a); o.y = w;
        w = stepf(w, bx3.y, a); o.z = w;
        w = stepf(w, bx3.z, a); o.w = w;
        __builtin_nontemporal_store(o, &outr[(size_t)j * 4 + 3]);

        // Advance across the chunk boundary (on the last chunk this consumes
        // x[1023]; the resulting w is unused — harmless).
        w = stepf(w, bx3.w, a);

        c0 = n0; c1 = n1; c2 = n2; c3 = n3;
    }
}

extern "C" void kernel_launch(void* const* d_in, const int* in_sizes, int n_in,
                              void* d_out, int out_size, void* d_ws, size_t ws_size,
                              hipStream_t stream) {
    const float* in = (const float*)d_in[0];
    const float* alpha = (const float*)d_in[1];
    const float* beta = (const float*)d_in[2];
    float* out = (float*)d_out;

    int total = in_sizes[0];      // l*p*m*n = 33554432
    int n_rows = total / N_COLS;  // 32768

    dim3 grid((n_rows + 63) / 64);
    dim3 block(64);
    DDK_77644418777662_kernel<<<grid, block, 0, stream>>>(in, out, alpha, beta,
                                                          n_rows);
}